// Round 15
// baseline (112.937 us; speedup 1.0000x reference)
//
#include <hip/hip_runtime.h>

#define NLAT 361
#define NLON 720
#define NF   361            // MMAX = rfft bins kept
#define NCH  32
#define NCK  (NCH * NLAT)   // 11552
#define KP   384            // stage2 K padded (per channel)
#define KD   768            // stage1 DFT K padded (n samples)
#define MD   384            // stage1 DFT M padded (f)
#define AROW 392            // stage2 LDS row stride for A (16B-unit stride 49: conflict-free)
#define BROW 72             // stage1 LDS row stride (f16): 9x16B odd -> conflict-free

typedef _Float16 h16;
typedef _Float16 f16x2 __attribute__((ext_vector_type(2)));
typedef _Float16 f16x4 __attribute__((ext_vector_type(4)));
typedef _Float16 f16x8 __attribute__((ext_vector_type(8)));
typedef float    f32x4 __attribute__((ext_vector_type(4)));

#define PLANE ((size_t)NF * NCH * KP)   // f16 elements per (re|im) plane

// Build padded f16 DFT matrices directly (scale folded in).
__global__ __launch_bounds__(256) void k_build_T(
    h16* __restrict__ Tre, h16* __restrict__ Tim) {
    int idx = blockIdx.x * 256 + threadIdx.x;
    if (idx >= MD * KD) return;
    int f = idx / KD, n = idx - f * KD;
    float re = 0.f, im = 0.f;
    if (f < NF && n < NLON) {
        int j = (f * n) % NLON;
        float ang = -6.283185307179586f * ((float)j / (float)NLON);
        float s, c;
        sincosf(ang, &s, &c);
        const float scale = 6.283185307179586f / (float)NLON;
        re = c * scale; im = s * scale;
    }
    Tre[idx] = (h16)re;
    Tim[idx] = (h16)im;
}

// Stage 1 (MFMA): xf[pl][f][c][klat] = sum_n T[pl][f][n] * x[c,klat][n]
// f-tile 128 (grid (3,181)): x is re-read 3x instead of 6x; same MFMA count.
__global__ __launch_bounds__(256) void k_stage1m(
    const float* __restrict__ x, const h16* __restrict__ Tre,
    const h16* __restrict__ Tim, h16* __restrict__ xfh) {
    __shared__ h16 As[2][128][BROW];   // 36,864 B
    __shared__ h16 Bs[64][BROW];       //  9,216 B
    const int t    = threadIdx.x;
    const int f0   = blockIdx.x * 128;
    const int n0   = blockIdx.y * 64;
    const int lane = t & 63, wv = t >> 6;
    const int wm   = wv & 1, wn = wv >> 1;   // wave tile: 64 f x 32 rows
    const int col  = lane & 15, kq = lane >> 4;

    f32x4 acc[2][4][2];   // [plane][mt][nt]
    #pragma unroll
    for (int p = 0; p < 2; ++p)
        #pragma unroll
        for (int a = 0; a < 4; ++a)
            #pragma unroll
            for (int b = 0; b < 2; ++b) acc[p][a][b] = (f32x4)0.0f;

    for (int ks = 0; ks < 12; ++ks) {
        __syncthreads();
        // stage A: 2 planes x 128 f-rows x 8 chunks = 2048 tasks, 8 iters
        #pragma unroll
        for (int i = 0; i < 8; ++i) {
            int task = t + i * 256;
            int pl   = task >> 10;
            int rem  = task & 1023;
            int r    = rem >> 3, ch = rem & 7;
            const h16* Tp = pl ? Tim : Tre;
            f16x8 v = *(const f16x8*)&Tp[(size_t)(f0 + r) * KD + ks * 64 + ch * 8];
            *(f16x8*)&As[pl][r][ch * 8] = v;
        }
        // stage B: x tile 64 rows x 64 n (f32 -> f16)
        #pragma unroll
        for (int p = 0; p < 4; ++p) {
            int r = p * 16 + (t >> 4), c4 = t & 15;
            int rowg = n0 + r;
            int n = ks * 64 + c4 * 4;
            float4 v = make_float4(0.f, 0.f, 0.f, 0.f);
            if (rowg < NCK && n < NLON)
                v = *(const float4*)&x[(size_t)rowg * NLON + n];
            f16x4 h = { (h16)v.x, (h16)v.y, (h16)v.z, (h16)v.w };
            *(f16x4*)&Bs[r][c4 * 4] = h;
        }
        __syncthreads();
        #pragma unroll
        for (int kk = 0; kk < 2; ++kk) {
            f16x8 bfr[2], afr[2][4];
            #pragma unroll
            for (int nt = 0; nt < 2; ++nt)
                bfr[nt] = *(const f16x8*)&Bs[wn * 32 + nt * 16 + col][kk * 32 + kq * 8];
            #pragma unroll
            for (int pl = 0; pl < 2; ++pl)
                #pragma unroll
                for (int mt = 0; mt < 4; ++mt)
                    afr[pl][mt] = *(const f16x8*)&As[pl][wm * 64 + mt * 16 + col][kk * 32 + kq * 8];
            #pragma unroll
            for (int pl = 0; pl < 2; ++pl)
                #pragma unroll
                for (int mt = 0; mt < 4; ++mt)
                    #pragma unroll
                    for (int nt = 0; nt < 2; ++nt)
                        acc[pl][mt][nt] = __builtin_amdgcn_mfma_f32_16x16x32_f16(
                            afr[pl][mt], bfr[nt], acc[pl][mt][nt], 0, 0, 0);
        }
    }

    #pragma unroll
    for (int nt = 0; nt < 2; ++nt) {
        int rowg = n0 + wn * 32 + nt * 16 + col;
        if (rowg >= NCK) continue;
        int c    = rowg / NLAT;
        int klat = rowg - c * NLAT;
        size_t cbase = (size_t)c * KP + klat;
        #pragma unroll
        for (int pl = 0; pl < 2; ++pl)
            #pragma unroll
            for (int mt = 0; mt < 4; ++mt)
                #pragma unroll
                for (int r = 0; r < 4; ++r) {
                    int f = f0 + wm * 64 + mt * 16 + kq * 4 + r;
                    if (f < NF)
                        xfh[(size_t)pl * PLANE + (size_t)f * NCH * KP + cbase] =
                            (h16)acc[pl][mt][nt][r];
                }
    }
}

// Stage 2 (MFMA): outws[m][c][l] = sum_k xf[m][c][k] * W[m][l][k]  (re,im)
// W[m][l][k] == 0 for l < m (Legendre triangle) -> only tiles lt >= m>>4.
// 713 blocks, XCD-chunked bijective swizzle so same-m blocks (sharing the
// A panel) land on the same XCD L2. W streamed through a 6-chunk f32
// register pipeline (2 ksteps each). Barrier-free K-loop. Output packed f16.
__global__ __launch_bounds__(512, 4) void k_stage2(
    const h16* __restrict__ xfh, const float* __restrict__ W,
    f16x2* __restrict__ outws) {
    __shared__ h16 Ah[2 * NCH * AROW];   // 50,176 B
    // bijective chunked swizzle: nwg=713, q=89, r=1 (m204 formula)
    const int b   = blockIdx.x;
    const int xcd = b & 7, ii = b >> 3;
    const int bid = (xcd == 0) ? ii : (90 + (xcd - 1) * 89 + ii);
    int m, g;
    if (bid < 336)      { m = bid / 3;                g = bid - 3 * m; }
    else if (bid < 592) { int r = bid - 336; m = 112 + (r >> 1); g = r & 1; }
    else                { m = 240 + (bid - 592);      g = 0; }

    const int t     = threadIdx.x;
    const int lane  = t & 63;
    const int wv    = t >> 6;                   // 0..7
    const int lt    = (m >> 4) + g * 8 + wv;    // needed tiles start at m>>4
    const bool ok   = (lt <= 22);
    const int col   = lane & 15;
    const int krow  = lane >> 4;                // 0..3
    const int krow8 = krow * 8;

    const float* Wm = W + (size_t)m * NLAT * NLAT;
    const int l     = lt * 16 + col;
    const int lsafe = (l < NLAT) ? l : (NLAT - 1);
    const float* wrow = Wm + (size_t)lsafe * NLAT + krow8;

    // stage A first (its loads overlap the W pipeline's waits).
    // Chunks covering klat>360 are zero-filled (replaces global memset).
    #pragma unroll
    for (int i = 0; i < 6; ++i) {
        int task = t + i * 512;
        int ri   = task / 1536;
        int rem  = task - ri * 1536;
        int c    = rem / 48, k8 = rem - c * 48;
        f16x8 v;
        if (k8 < 46) {
            v = *(const f16x8*)&xfh[(size_t)ri * PLANE + ((size_t)(m * NCH + c)) * KP + k8 * 8];
        } else {
            #pragma unroll
            for (int e = 0; e < 8; ++e) v[e] = (h16)0.f;
        }
        if (k8 == 45) {
            #pragma unroll
            for (int e = 1; e < 8; ++e) v[e] = (h16)0.f;   // klat 361..367
        }
        *(f16x8*)&Ah[(ri * NCH + c) * AROW + k8 * 8] = v;
    }

    // W pipeline: 6 chunks x (2 ksteps x 8 dwords). wa/wb double-buffer.
    // Reads up to k=383 run into the next row (garbage x A-pad-zero = 0);
    // <=88B past W end on the very last row, within allocation slack.
    f16x8 wh[12];
    float wa[16], wb[16];
    if (ok) {
        #pragma unroll
        for (int e = 0; e < 16; ++e) wa[e] = wrow[(e >> 3) * 32 + (e & 7)];        // ks 0,1
        #pragma unroll
        for (int e = 0; e < 16; ++e) wb[e] = wrow[(2 + (e >> 3)) * 32 + (e & 7)];  // ks 2,3
    } else {
        #pragma unroll
        for (int e = 0; e < 16; ++e) { wa[e] = 0.f; wb[e] = 0.f; }
    }
    #pragma unroll
    for (int cc = 0; cc < 6; ++cc) {
        float* cur = (cc & 1) ? wb : wa;   // static after full unroll
        #pragma unroll
        for (int h = 0; h < 2; ++h)
            #pragma unroll
            for (int e = 0; e < 8; ++e)
                wh[cc * 2 + h][e] = (h16)cur[h * 8 + e];
        if (cc < 4 && ok) {
            #pragma unroll
            for (int e = 0; e < 16; ++e)
                cur[e] = wrow[((cc * 2 + 4) + (e >> 3)) * 32 + (e & 7)];
        }
    }

    f32x4 acc[2][2];   // [ct][plane]
    #pragma unroll
    for (int ct = 0; ct < 2; ++ct)
        #pragma unroll
        for (int pl = 0; pl < 2; ++pl)
            acc[ct][pl] = (f32x4)0.0f;

    __syncthreads();   // Ah visible; the ONLY barrier

    #pragma unroll
    for (int ks = 0; ks < 12; ++ks) {
        f16x8 af[2][2];
        #pragma unroll
        for (int pl = 0; pl < 2; ++pl)
            #pragma unroll
            for (int ct = 0; ct < 2; ++ct)
                af[pl][ct] = *(const f16x8*)&Ah[(pl * NCH + ct * 16 + col) * AROW + ks * 32 + krow8];

        #pragma unroll
        for (int ct = 0; ct < 2; ++ct)
            #pragma unroll
            for (int pl = 0; pl < 2; ++pl)
                acc[ct][pl] = __builtin_amdgcn_mfma_f32_16x16x32_f16(
                    af[pl][ct], wh[ks], acc[ct][pl], 0, 0, 0);
    }

    // epilogue: D col(l)=lane&15, row(c)=(lane>>4)*4+reg; pack re|im as 2xf16
    if (ok && l < NLAT) {
        #pragma unroll
        for (int ct = 0; ct < 2; ++ct) {
            #pragma unroll
            for (int r = 0; r < 4; ++r) {
                int c = ct * 16 + krow * 4 + r;
                f16x2 p;
                p[0] = (h16)acc[ct][0][r];
                p[1] = (h16)acc[ct][1][r];
                outws[((size_t)m * NCH + c) * NLAT + l] = p;
            }
        }
    }
}

// Transpose: out[cl][m] = ws[m][cl]  (packed f16 -> float2), 361 x 11552.
// out is exactly 0 for l < m (Legendre triangle) — write zeros there.
__global__ __launch_bounds__(256) void k_transpose(
    const f16x2* __restrict__ src, float2* __restrict__ dst) {
    __shared__ f16x2 tile[32][33];
    const int tx = threadIdx.x & 31, ty = threadIdx.x >> 5;
    const int cl0 = blockIdx.x * 32, m0 = blockIdx.y * 32;
    #pragma unroll
    for (int i = 0; i < 4; ++i) {
        int mm = m0 + ty + i * 8;
        if (mm < NLAT) tile[ty + i * 8][tx] = src[(size_t)mm * NCK + cl0 + tx];
    }
    __syncthreads();
    #pragma unroll
    for (int i = 0; i < 4; ++i) {
        int mm = m0 + tx;
        int cl = cl0 + ty + i * 8;
        if (mm < NLAT) {
            int l = cl - (cl / NLAT) * NLAT;
            float2 v;
            if (l < mm) {
                v = make_float2(0.f, 0.f);
            } else {
                f16x2 p = tile[tx][ty + i * 8];
                v = make_float2((float)p[0], (float)p[1]);
            }
            dst[(size_t)cl * NLAT + mm] = v;
        }
    }
}

extern "C" void kernel_launch(void* const* d_in, const int* in_sizes, int n_in,
                              void* d_out, int out_size, void* d_ws, size_t ws_size,
                              hipStream_t stream) {
    const float* x = (const float*)d_in[0];
    const float* W = (const float*)d_in[1];
    float2* out2 = (float2*)d_out;

    char* ws = (char*)d_ws;
    h16*    Tre   = (h16*)(ws + 8192);
    h16*    Tim   = (h16*)(ws + 8192 + 589824);
    h16*    xfh   = (h16*)(ws + 1187840);
    f16x2*  outws = (f16x2*)(ws + 1187840 + 2 * PLANE * sizeof(h16));

    k_build_T<<<(MD * KD + 255) / 256, 256, 0, stream>>>(Tre, Tim);
    k_stage1m<<<dim3(3, 181), 256, 0, stream>>>(x, Tre, Tim, xfh);
    k_stage2<<<713, 512, 0, stream>>>(xfh, W, outws);
    k_transpose<<<dim3(361, 12), 256, 0, stream>>>(outws, out2);
}

// Round 17
// 93.967 us; speedup vs baseline: 1.2019x; 1.2019x over previous
//
#include <hip/hip_runtime.h>

#define NLAT 361
#define NLON 720
#define NF   361            // MMAX = rfft bins kept
#define NCH  32
#define NCK  (NCH * NLAT)   // 11552
#define KP   384            // stage2 K padded (per channel)
#define KD   768            // stage1 DFT K padded (n samples)
#define MD   384            // stage1 DFT M padded (f)
#define AROW 392            // stage2 LDS row stride for A (16B-unit stride 49: conflict-free)
#define BROW 72             // stage1 LDS row stride (f16)

typedef _Float16 h16;
typedef _Float16 f16x2 __attribute__((ext_vector_type(2)));
typedef _Float16 f16x4 __attribute__((ext_vector_type(4)));
typedef _Float16 f16x8 __attribute__((ext_vector_type(8)));
typedef float    f32x4 __attribute__((ext_vector_type(4)));
typedef float    f4u   __attribute__((vector_size(16), aligned(4)));  // dword-aligned float4

#define PLANE ((size_t)NF * NCH * KP)   // f16 elements per (re|im) plane

// Build padded f16 DFT matrices directly (scale folded in).
__global__ __launch_bounds__(256) void k_build_T(
    h16* __restrict__ Tre, h16* __restrict__ Tim) {
    int idx = blockIdx.x * 256 + threadIdx.x;
    if (idx >= MD * KD) return;
    int f = idx / KD, n = idx - f * KD;
    float re = 0.f, im = 0.f;
    if (f < NF && n < NLON) {
        int j = (f * n) % NLON;
        float ang = -6.283185307179586f * ((float)j / (float)NLON);
        float s, c;
        sincosf(ang, &s, &c);
        const float scale = 6.283185307179586f / (float)NLON;
        re = c * scale; im = s * scale;
    }
    Tre[idx] = (h16)re;
    Tim[idx] = (h16)im;
}

// Stage 1 (MFMA): xf[pl][f][c][klat] = sum_n T[pl][f][n] * x[c,klat][n]
__global__ __launch_bounds__(256) void k_stage1m(
    const float* __restrict__ x, const h16* __restrict__ Tre,
    const h16* __restrict__ Tim, h16* __restrict__ xfh) {
    __shared__ h16 As[2][64][BROW];
    __shared__ h16 Bs[64][BROW];
    const int t    = threadIdx.x;
    const int f0   = blockIdx.x * 64;
    const int n0   = blockIdx.y * 64;
    const int lane = t & 63, wv = t >> 6;
    const int wm   = wv & 1, wn = wv >> 1;
    const int col  = lane & 15, kq = lane >> 4;

    f32x4 acc[2][2][2];
    #pragma unroll
    for (int p = 0; p < 2; ++p)
        #pragma unroll
        for (int a = 0; a < 2; ++a)
            #pragma unroll
            for (int b = 0; b < 2; ++b) acc[p][a][b] = (f32x4)0.0f;

    for (int ks = 0; ks < 12; ++ks) {
        __syncthreads();
        #pragma unroll
        for (int i = 0; i < 4; ++i) {
            int task = t + i * 256;
            int pl   = task >> 9;
            int rem  = task & 511;
            int r    = rem >> 3, ch = rem & 7;
            const h16* Tp = pl ? Tim : Tre;
            f16x8 v = *(const f16x8*)&Tp[(size_t)(f0 + r) * KD + ks * 64 + ch * 8];
            *(f16x8*)&As[pl][r][ch * 8] = v;
        }
        #pragma unroll
        for (int p = 0; p < 4; ++p) {
            int r = p * 16 + (t >> 4), c4 = t & 15;
            int rowg = n0 + r;
            int n = ks * 64 + c4 * 4;
            float4 v = make_float4(0.f, 0.f, 0.f, 0.f);
            if (rowg < NCK && n < NLON)
                v = *(const float4*)&x[(size_t)rowg * NLON + n];
            f16x4 h = { (h16)v.x, (h16)v.y, (h16)v.z, (h16)v.w };
            *(f16x4*)&Bs[r][c4 * 4] = h;
        }
        __syncthreads();
        #pragma unroll
        for (int kk = 0; kk < 2; ++kk) {
            f16x8 bfr[2], afr[2][2];
            #pragma unroll
            for (int nt = 0; nt < 2; ++nt)
                bfr[nt] = *(const f16x8*)&Bs[wn * 32 + nt * 16 + col][kk * 32 + kq * 8];
            #pragma unroll
            for (int pl = 0; pl < 2; ++pl)
                #pragma unroll
                for (int mt = 0; mt < 2; ++mt)
                    afr[pl][mt] = *(const f16x8*)&As[pl][wm * 32 + mt * 16 + col][kk * 32 + kq * 8];
            #pragma unroll
            for (int pl = 0; pl < 2; ++pl)
                #pragma unroll
                for (int mt = 0; mt < 2; ++mt)
                    #pragma unroll
                    for (int nt = 0; nt < 2; ++nt)
                        acc[pl][mt][nt] = __builtin_amdgcn_mfma_f32_16x16x32_f16(
                            afr[pl][mt], bfr[nt], acc[pl][mt][nt], 0, 0, 0);
        }
    }

    #pragma unroll
    for (int nt = 0; nt < 2; ++nt) {
        int rowg = n0 + wn * 32 + nt * 16 + col;
        if (rowg >= NCK) continue;
        int c    = rowg / NLAT;
        int klat = rowg - c * NLAT;
        size_t cbase = (size_t)c * KP + klat;
        #pragma unroll
        for (int pl = 0; pl < 2; ++pl)
            #pragma unroll
            for (int mt = 0; mt < 2; ++mt)
                #pragma unroll
                for (int r = 0; r < 4; ++r) {
                    int f = f0 + wm * 32 + mt * 16 + kq * 4 + r;
                    if (f < NF)
                        xfh[(size_t)pl * PLANE + (size_t)f * NCH * KP + cbase] =
                            (h16)acc[pl][mt][nt][r];
                }
    }
}

// Stage 2 (MFMA): outws[m][c][l] = sum_k xf[m][c][k] * W[m][l][k]  (re,im)
// W[m][l][k] == 0 for l < m (Legendre triangle) -> only tiles lt >= m>>4.
// 713 blocks, XCD-chunked bijective swizzle. W streamed through a 6-chunk
// register pipeline with dword-aligned dwordx4 loads (2 per kstep per lane
// instead of 8 scalar dwords). Barrier-free K-loop. Output packed f16.
__global__ __launch_bounds__(512, 4) void k_stage2(
    const h16* __restrict__ xfh, const float* __restrict__ W,
    f16x2* __restrict__ outws) {
    __shared__ h16 Ah[2 * NCH * AROW];   // 50,176 B
    // bijective chunked swizzle: nwg=713, q=89, r=1 (m204 formula)
    const int b   = blockIdx.x;
    const int xcd = b & 7, ii = b >> 3;
    const int bid = (xcd == 0) ? ii : (90 + (xcd - 1) * 89 + ii);
    int m, g;
    if (bid < 336)      { m = bid / 3;                g = bid - 3 * m; }
    else if (bid < 592) { int r = bid - 336; m = 112 + (r >> 1); g = r & 1; }
    else                { m = 240 + (bid - 592);      g = 0; }

    const int t     = threadIdx.x;
    const int lane  = t & 63;
    const int wv    = t >> 6;                   // 0..7
    const int lt    = (m >> 4) + g * 8 + wv;    // needed tiles start at m>>4
    const bool ok   = (lt <= 22);
    const int col   = lane & 15;
    const int krow  = lane >> 4;                // 0..3
    const int krow8 = krow * 8;

    const float* Wm = W + (size_t)m * NLAT * NLAT;
    const int l     = lt * 16 + col;
    const int lsafe = (l < NLAT) ? l : (NLAT - 1);
    const float* wrow = Wm + (size_t)lsafe * NLAT + krow8;

    // stage A first (its loads overlap the W pipeline's waits).
    // Chunks covering klat>360 are zero-filled (replaces global memset).
    #pragma unroll
    for (int i = 0; i < 6; ++i) {
        int task = t + i * 512;
        int ri   = task / 1536;
        int rem  = task - ri * 1536;
        int c    = rem / 48, k8 = rem - c * 48;
        f16x8 v;
        if (k8 < 46) {
            v = *(const f16x8*)&xfh[(size_t)ri * PLANE + ((size_t)(m * NCH + c)) * KP + k8 * 8];
        } else {
            #pragma unroll
            for (int e = 0; e < 8; ++e) v[e] = (h16)0.f;
        }
        if (k8 == 45) {
            #pragma unroll
            for (int e = 1; e < 8; ++e) v[e] = (h16)0.f;   // klat 361..367
        }
        *(f16x8*)&Ah[(ri * NCH + c) * AROW + k8 * 8] = v;
    }

    // W pipeline: 6 chunks x (2 ksteps x 2 dwordx4/lane). wa/wb double-buffer.
    // Reads up to k=383 run into the next row (garbage x A-pad-zero = 0);
    // <=88B past W end on the very last row, within allocation slack.
    f16x8 wh[12];
    f4u wa[4], wb[4];
    if (ok) {
        #pragma unroll
        for (int h = 0; h < 2; ++h)
            #pragma unroll
            for (int q = 0; q < 2; ++q) {
                wa[h * 2 + q] = *(const f4u*)&wrow[h * 32 + q * 4];         // ks 0,1
                wb[h * 2 + q] = *(const f4u*)&wrow[(2 + h) * 32 + q * 4];   // ks 2,3
            }
    } else {
        #pragma unroll
        for (int e = 0; e < 4; ++e)
            #pragma unroll
            for (int j = 0; j < 4; ++j) { wa[e][j] = 0.f; wb[e][j] = 0.f; }
    }
    #pragma unroll
    for (int cc = 0; cc < 6; ++cc) {
        f4u* cur = (cc & 1) ? wb : wa;   // static after full unroll
        #pragma unroll
        for (int h = 0; h < 2; ++h)
            #pragma unroll
            for (int e = 0; e < 8; ++e)
                wh[cc * 2 + h][e] = (h16)cur[h * 2 + (e >> 2)][e & 3];
        if (cc < 4 && ok) {
            #pragma unroll
            for (int h = 0; h < 2; ++h)
                #pragma unroll
                for (int q = 0; q < 2; ++q)
                    cur[h * 2 + q] = *(const f4u*)&wrow[((cc * 2 + 4) + h) * 32 + q * 4];
        }
    }

    f32x4 acc[2][2];   // [ct][plane]
    #pragma unroll
    for (int ct = 0; ct < 2; ++ct)
        #pragma unroll
        for (int pl = 0; pl < 2; ++pl)
            acc[ct][pl] = (f32x4)0.0f;

    __syncthreads();   // Ah visible; the ONLY barrier

    #pragma unroll
    for (int ks = 0; ks < 12; ++ks) {
        f16x8 af[2][2];
        #pragma unroll
        for (int pl = 0; pl < 2; ++pl)
            #pragma unroll
            for (int ct = 0; ct < 2; ++ct)
                af[pl][ct] = *(const f16x8*)&Ah[(pl * NCH + ct * 16 + col) * AROW + ks * 32 + krow8];

        #pragma unroll
        for (int ct = 0; ct < 2; ++ct)
            #pragma unroll
            for (int pl = 0; pl < 2; ++pl)
                acc[ct][pl] = __builtin_amdgcn_mfma_f32_16x16x32_f16(
                    af[pl][ct], wh[ks], acc[ct][pl], 0, 0, 0);
    }

    // epilogue: D col(l)=lane&15, row(c)=(lane>>4)*4+reg; pack re|im as 2xf16
    if (ok && l < NLAT) {
        #pragma unroll
        for (int ct = 0; ct < 2; ++ct) {
            #pragma unroll
            for (int r = 0; r < 4; ++r) {
                int c = ct * 16 + krow * 4 + r;
                f16x2 p;
                p[0] = (h16)acc[ct][0][r];
                p[1] = (h16)acc[ct][1][r];
                outws[((size_t)m * NCH + c) * NLAT + l] = p;
            }
        }
    }
}

// Transpose: out[cl][m] = ws[m][cl]  (packed f16 -> float2), 361 x 11552.
// out is exactly 0 for l < m (Legendre triangle) — write zeros there.
__global__ __launch_bounds__(256) void k_transpose(
    const f16x2* __restrict__ src, float2* __restrict__ dst) {
    __shared__ f16x2 tile[32][33];
    const int tx = threadIdx.x & 31, ty = threadIdx.x >> 5;
    const int cl0 = blockIdx.x * 32, m0 = blockIdx.y * 32;
    #pragma unroll
    for (int i = 0; i < 4; ++i) {
        int mm = m0 + ty + i * 8;
        if (mm < NLAT) tile[ty + i * 8][tx] = src[(size_t)mm * NCK + cl0 + tx];
    }
    __syncthreads();
    #pragma unroll
    for (int i = 0; i < 4; ++i) {
        int mm = m0 + tx;
        int cl = cl0 + ty + i * 8;
        if (mm < NLAT) {
            int l = cl - (cl / NLAT) * NLAT;
            float2 v;
            if (l < mm) {
                v = make_float2(0.f, 0.f);
            } else {
                f16x2 p = tile[tx][ty + i * 8];
                v = make_float2((float)p[0], (float)p[1]);
            }
            dst[(size_t)cl * NLAT + mm] = v;
        }
    }
}

extern "C" void kernel_launch(void* const* d_in, const int* in_sizes, int n_in,
                              void* d_out, int out_size, void* d_ws, size_t ws_size,
                              hipStream_t stream) {
    const float* x = (const float*)d_in[0];
    const float* W = (const float*)d_in[1];
    float2* out2 = (float2*)d_out;

    char* ws = (char*)d_ws;
    h16*    Tre   = (h16*)(ws + 8192);
    h16*    Tim   = (h16*)(ws + 8192 + 589824);
    h16*    xfh   = (h16*)(ws + 1187840);
    f16x2*  outws = (f16x2*)(ws + 1187840 + 2 * PLANE * sizeof(h16));

    k_build_T<<<(MD * KD + 255) / 256, 256, 0, stream>>>(Tre, Tim);
    k_stage1m<<<dim3(6, 181), 256, 0, stream>>>(x, Tre, Tim, xfh);
    k_stage2<<<713, 512, 0, stream>>>(xfh, W, outws);
    k_transpose<<<dim3(361, 12), 256, 0, stream>>>(outws, out2);
}

// Round 18
// 86.562 us; speedup vs baseline: 1.3047x; 1.0855x over previous
//
#include <hip/hip_runtime.h>

#define NLAT 361
#define NLON 720
#define NF   361            // MMAX = rfft bins kept
#define NCH  32
#define NCK  (NCH * NLAT)   // 11552
#define KP   384            // stage2 K padded (per channel)
#define KD   768            // stage1 DFT K padded (n samples)
#define MD   384            // stage1 DFT M padded (f)
#define AROW 392            // stage2 LDS row stride for A (16B-unit stride 49: conflict-free)
#define BROW 72             // stage1 LDS row stride (f16)

typedef _Float16 h16;
typedef _Float16 f16x2 __attribute__((ext_vector_type(2)));
typedef _Float16 f16x4 __attribute__((ext_vector_type(4)));
typedef _Float16 f16x8 __attribute__((ext_vector_type(8)));
typedef float    f32x4 __attribute__((ext_vector_type(4)));
typedef float    f4u   __attribute__((vector_size(16), aligned(4)));  // dword-aligned float4

#define PLANE ((size_t)NF * NCH * KP)   // f16 elements per (re|im) plane

// Build padded f16 DFT matrices directly (scale folded in).
__global__ __launch_bounds__(256) void k_build_T(
    h16* __restrict__ Tre, h16* __restrict__ Tim) {
    int idx = blockIdx.x * 256 + threadIdx.x;
    if (idx >= MD * KD) return;
    int f = idx / KD, n = idx - f * KD;
    float re = 0.f, im = 0.f;
    if (f < NF && n < NLON) {
        int j = (f * n) % NLON;
        float ang = -6.283185307179586f * ((float)j / (float)NLON);
        float s, c;
        sincosf(ang, &s, &c);
        const float scale = 6.283185307179586f / (float)NLON;
        re = c * scale; im = s * scale;
    }
    Tre[idx] = (h16)re;
    Tim[idx] = (h16)im;
}

// Stage 1 (MFMA): xf[pl][f][c][klat] = sum_n T[pl][f][n] * x[c,klat][n]
// 1D grid of 1086 with XCD-chunked swizzle: the 6 f-tiles sharing one x
// row-tile get consecutive orig ids -> same XCD -> x tile is L2-resident
// (fetched once, hit 5x) instead of re-fetched from L3 by 6 XCDs.
__global__ __launch_bounds__(256) void k_stage1m(
    const float* __restrict__ x, const h16* __restrict__ Tre,
    const h16* __restrict__ Tim, h16* __restrict__ xfh) {
    __shared__ h16 As[2][64][BROW];
    __shared__ h16 Bs[64][BROW];
    // chunked bijective swizzle, nwg=1086 (= 6 mod 8): XCD k<6 owns 136
    // consecutive orig ids starting k*136; k>=6 owns 135 starting 816+(k-6)*135.
    const int bhw = blockIdx.x;
    const int xcd = bhw & 7, ii = bhw >> 3;
    const int orig = ((xcd < 6) ? xcd * 136 : 816 + (xcd - 6) * 135) + ii;
    const int ytile = orig / 6, ftile = orig - ytile * 6;

    const int t    = threadIdx.x;
    const int f0   = ftile * 64;
    const int n0   = ytile * 64;
    const int lane = t & 63, wv = t >> 6;
    const int wm   = wv & 1, wn = wv >> 1;
    const int col  = lane & 15, kq = lane >> 4;

    f32x4 acc[2][2][2];
    #pragma unroll
    for (int p = 0; p < 2; ++p)
        #pragma unroll
        for (int a = 0; a < 2; ++a)
            #pragma unroll
            for (int b = 0; b < 2; ++b) acc[p][a][b] = (f32x4)0.0f;

    for (int ks = 0; ks < 12; ++ks) {
        __syncthreads();
        #pragma unroll
        for (int i = 0; i < 4; ++i) {
            int task = t + i * 256;
            int pl   = task >> 9;
            int rem  = task & 511;
            int r    = rem >> 3, ch = rem & 7;
            const h16* Tp = pl ? Tim : Tre;
            f16x8 v = *(const f16x8*)&Tp[(size_t)(f0 + r) * KD + ks * 64 + ch * 8];
            *(f16x8*)&As[pl][r][ch * 8] = v;
        }
        #pragma unroll
        for (int p = 0; p < 4; ++p) {
            int r = p * 16 + (t >> 4), c4 = t & 15;
            int rowg = n0 + r;
            int n = ks * 64 + c4 * 4;
            float4 v = make_float4(0.f, 0.f, 0.f, 0.f);
            if (rowg < NCK && n < NLON)
                v = *(const float4*)&x[(size_t)rowg * NLON + n];
            f16x4 h = { (h16)v.x, (h16)v.y, (h16)v.z, (h16)v.w };
            *(f16x4*)&Bs[r][c4 * 4] = h;
        }
        __syncthreads();
        #pragma unroll
        for (int kk = 0; kk < 2; ++kk) {
            f16x8 bfr[2], afr[2][2];
            #pragma unroll
            for (int nt = 0; nt < 2; ++nt)
                bfr[nt] = *(const f16x8*)&Bs[wn * 32 + nt * 16 + col][kk * 32 + kq * 8];
            #pragma unroll
            for (int pl = 0; pl < 2; ++pl)
                #pragma unroll
                for (int mt = 0; mt < 2; ++mt)
                    afr[pl][mt] = *(const f16x8*)&As[pl][wm * 32 + mt * 16 + col][kk * 32 + kq * 8];
            #pragma unroll
            for (int pl = 0; pl < 2; ++pl)
                #pragma unroll
                for (int mt = 0; mt < 2; ++mt)
                    #pragma unroll
                    for (int nt = 0; nt < 2; ++nt)
                        acc[pl][mt][nt] = __builtin_amdgcn_mfma_f32_16x16x32_f16(
                            afr[pl][mt], bfr[nt], acc[pl][mt][nt], 0, 0, 0);
        }
    }

    #pragma unroll
    for (int nt = 0; nt < 2; ++nt) {
        int rowg = n0 + wn * 32 + nt * 16 + col;
        if (rowg >= NCK) continue;
        int c    = rowg / NLAT;
        int klat = rowg - c * NLAT;
        size_t cbase = (size_t)c * KP + klat;
        #pragma unroll
        for (int pl = 0; pl < 2; ++pl)
            #pragma unroll
            for (int mt = 0; mt < 2; ++mt)
                #pragma unroll
                for (int r = 0; r < 4; ++r) {
                    int f = f0 + wm * 32 + mt * 16 + kq * 4 + r;
                    if (f < NF)
                        xfh[(size_t)pl * PLANE + (size_t)f * NCH * KP + cbase] =
                            (h16)acc[pl][mt][nt][r];
                }
    }
}

// Stage 2 (MFMA): outws[m][c][l] = sum_k xf[m][c][k] * W[m][l][k]  (re,im)
// W[m][l][k] == 0 for l < m (Legendre triangle) -> only tiles lt >= m>>4.
// 713 blocks, XCD-chunked bijective swizzle. W streamed through a 6-chunk
// register pipeline with dword-aligned dwordx4 loads. Barrier-free K-loop.
// Output packed f16.
__global__ __launch_bounds__(512, 4) void k_stage2(
    const h16* __restrict__ xfh, const float* __restrict__ W,
    f16x2* __restrict__ outws) {
    __shared__ h16 Ah[2 * NCH * AROW];   // 50,176 B
    // bijective chunked swizzle: nwg=713, q=89, r=1 (m204 formula)
    const int b   = blockIdx.x;
    const int xcd = b & 7, ii = b >> 3;
    const int bid = (xcd == 0) ? ii : (90 + (xcd - 1) * 89 + ii);
    int m, g;
    if (bid < 336)      { m = bid / 3;                g = bid - 3 * m; }
    else if (bid < 592) { int r = bid - 336; m = 112 + (r >> 1); g = r & 1; }
    else                { m = 240 + (bid - 592);      g = 0; }

    const int t     = threadIdx.x;
    const int lane  = t & 63;
    const int wv    = t >> 6;                   // 0..7
    const int lt    = (m >> 4) + g * 8 + wv;    // needed tiles start at m>>4
    const bool ok   = (lt <= 22);
    const int col   = lane & 15;
    const int krow  = lane >> 4;                // 0..3
    const int krow8 = krow * 8;

    const float* Wm = W + (size_t)m * NLAT * NLAT;
    const int l     = lt * 16 + col;
    const int lsafe = (l < NLAT) ? l : (NLAT - 1);
    const float* wrow = Wm + (size_t)lsafe * NLAT + krow8;

    // stage A first (its loads overlap the W pipeline's waits).
    // Chunks covering klat>360 are zero-filled (replaces global memset).
    #pragma unroll
    for (int i = 0; i < 6; ++i) {
        int task = t + i * 512;
        int ri   = task / 1536;
        int rem  = task - ri * 1536;
        int c    = rem / 48, k8 = rem - c * 48;
        f16x8 v;
        if (k8 < 46) {
            v = *(const f16x8*)&xfh[(size_t)ri * PLANE + ((size_t)(m * NCH + c)) * KP + k8 * 8];
        } else {
            #pragma unroll
            for (int e = 0; e < 8; ++e) v[e] = (h16)0.f;
        }
        if (k8 == 45) {
            #pragma unroll
            for (int e = 1; e < 8; ++e) v[e] = (h16)0.f;   // klat 361..367
        }
        *(f16x8*)&Ah[(ri * NCH + c) * AROW + k8 * 8] = v;
    }

    // W pipeline: 6 chunks x (2 ksteps x 2 dwordx4/lane). wa/wb double-buffer.
    // Reads up to k=383 run into the next row (garbage x A-pad-zero = 0);
    // <=88B past W end on the very last row, within allocation slack.
    f16x8 wh[12];
    f4u wa[4], wb[4];
    if (ok) {
        #pragma unroll
        for (int h = 0; h < 2; ++h)
            #pragma unroll
            for (int q = 0; q < 2; ++q) {
                wa[h * 2 + q] = *(const f4u*)&wrow[h * 32 + q * 4];         // ks 0,1
                wb[h * 2 + q] = *(const f4u*)&wrow[(2 + h) * 32 + q * 4];   // ks 2,3
            }
    } else {
        #pragma unroll
        for (int e = 0; e < 4; ++e)
            #pragma unroll
            for (int j = 0; j < 4; ++j) { wa[e][j] = 0.f; wb[e][j] = 0.f; }
    }
    #pragma unroll
    for (int cc = 0; cc < 6; ++cc) {
        f4u* cur = (cc & 1) ? wb : wa;   // static after full unroll
        #pragma unroll
        for (int h = 0; h < 2; ++h)
            #pragma unroll
            for (int e = 0; e < 8; ++e)
                wh[cc * 2 + h][e] = (h16)cur[h * 2 + (e >> 2)][e & 3];
        if (cc < 4 && ok) {
            #pragma unroll
            for (int h = 0; h < 2; ++h)
                #pragma unroll
                for (int q = 0; q < 2; ++q)
                    cur[h * 2 + q] = *(const f4u*)&wrow[((cc * 2 + 4) + h) * 32 + q * 4];
        }
    }

    f32x4 acc[2][2];   // [ct][plane]
    #pragma unroll
    for (int ct = 0; ct < 2; ++ct)
        #pragma unroll
        for (int pl = 0; pl < 2; ++pl)
            acc[ct][pl] = (f32x4)0.0f;

    __syncthreads();   // Ah visible; the ONLY barrier

    #pragma unroll
    for (int ks = 0; ks < 12; ++ks) {
        f16x8 af[2][2];
        #pragma unroll
        for (int pl = 0; pl < 2; ++pl)
            #pragma unroll
            for (int ct = 0; ct < 2; ++ct)
                af[pl][ct] = *(const f16x8*)&Ah[(pl * NCH + ct * 16 + col) * AROW + ks * 32 + krow8];

        #pragma unroll
        for (int ct = 0; ct < 2; ++ct)
            #pragma unroll
            for (int pl = 0; pl < 2; ++pl)
                acc[ct][pl] = __builtin_amdgcn_mfma_f32_16x16x32_f16(
                    af[pl][ct], wh[ks], acc[ct][pl], 0, 0, 0);
    }

    // epilogue: D col(l)=lane&15, row(c)=(lane>>4)*4+reg; pack re|im as 2xf16
    if (ok && l < NLAT) {
        #pragma unroll
        for (int ct = 0; ct < 2; ++ct) {
            #pragma unroll
            for (int r = 0; r < 4; ++r) {
                int c = ct * 16 + krow * 4 + r;
                f16x2 p;
                p[0] = (h16)acc[ct][0][r];
                p[1] = (h16)acc[ct][1][r];
                outws[((size_t)m * NCH + c) * NLAT + l] = p;
            }
        }
    }
}

// Transpose: out[cl][m] = ws[m][cl]  (packed f16 -> float2), 361 x 11552.
// out is exactly 0 for l < m (Legendre triangle) — write zeros there.
__global__ __launch_bounds__(256) void k_transpose(
    const f16x2* __restrict__ src, float2* __restrict__ dst) {
    __shared__ f16x2 tile[32][33];
    const int tx = threadIdx.x & 31, ty = threadIdx.x >> 5;
    const int cl0 = blockIdx.x * 32, m0 = blockIdx.y * 32;
    #pragma unroll
    for (int i = 0; i < 4; ++i) {
        int mm = m0 + ty + i * 8;
        if (mm < NLAT) tile[ty + i * 8][tx] = src[(size_t)mm * NCK + cl0 + tx];
    }
    __syncthreads();
    #pragma unroll
    for (int i = 0; i < 4; ++i) {
        int mm = m0 + tx;
        int cl = cl0 + ty + i * 8;
        if (mm < NLAT) {
            int l = cl - (cl / NLAT) * NLAT;
            float2 v;
            if (l < mm) {
                v = make_float2(0.f, 0.f);
            } else {
                f16x2 p = tile[tx][ty + i * 8];
                v = make_float2((float)p[0], (float)p[1]);
            }
            dst[(size_t)cl * NLAT + mm] = v;
        }
    }
}

extern "C" void kernel_launch(void* const* d_in, const int* in_sizes, int n_in,
                              void* d_out, int out_size, void* d_ws, size_t ws_size,
                              hipStream_t stream) {
    const float* x = (const float*)d_in[0];
    const float* W = (const float*)d_in[1];
    float2* out2 = (float2*)d_out;

    char* ws = (char*)d_ws;
    h16*    Tre   = (h16*)(ws + 8192);
    h16*    Tim   = (h16*)(ws + 8192 + 589824);
    h16*    xfh   = (h16*)(ws + 1187840);
    f16x2*  outws = (f16x2*)(ws + 1187840 + 2 * PLANE * sizeof(h16));

    k_build_T<<<(MD * KD + 255) / 256, 256, 0, stream>>>(Tre, Tim);
    k_stage1m<<<1086, 256, 0, stream>>>(x, Tre, Tim, xfh);
    k_stage2<<<713, 512, 0, stream>>>(xfh, W, outws);
    k_transpose<<<dim3(361, 12), 256, 0, stream>>>(outws, out2);
}